// Round 1
// baseline (288.801 us; speedup 1.0000x reference)
//
#include <hip/hip_runtime.h>

#define N_NODES 4096
#define N_EDGES 16384
#define FN 128
#define FE 64

#define NBI 32
#define NBJ 32
#define NJS 8

#define EBI 64
#define EBJ 32
#define EJS 16

__device__ __forceinline__ float lrelu(float x) { return x >= 0.f ? x : 0.01f * x; }

// ---- kernel 1: per-node h = nf@Wn row, then alpha/beta/gamma dots (h never stored) ----
__global__ __launch_bounds__(256) void k_node_proj(
    const float* __restrict__ nf, const float* __restrict__ Wn,
    const float* __restrict__ pvn, const float* __restrict__ pve,
    float* __restrict__ alpha, float* __restrict__ beta, float* __restrict__ gamma) {
    __shared__ float row[4][FN];
    const int wv = threadIdx.x >> 6, ln = threadIdx.x & 63;
    const int i = blockIdx.x * 4 + wv;
    float2 r2 = *(const float2*)(nf + (size_t)i * FN + ln * 2);
    row[wv][ln * 2] = r2.x; row[wv][ln * 2 + 1] = r2.y;
    __syncthreads();
    float h0 = 0.f, h1 = 0.f;
#pragma unroll 8
    for (int k = 0; k < FN; ++k) {
        float nv = row[wv][k];
        float2 w2 = *(const float2*)(Wn + (size_t)k * FN + ln * 2);
        h0 = fmaf(nv, w2.x, h0); h1 = fmaf(nv, w2.y, h1);
    }
    float2 as = *(const float2*)(pvn + ln * 2);
    float2 an = *(const float2*)(pvn + FN + ln * 2);
    float2 bs = *(const float2*)(pve + ln * 2);
    float pa = h0 * as.x + h1 * as.y;
    float pb = h0 * an.x + h1 * an.y;
    float pg = h0 * bs.x + h1 * bs.y;
#pragma unroll
    for (int off = 32; off > 0; off >>= 1) {
        pa += __shfl_down(pa, off, 64);
        pb += __shfl_down(pb, off, 64);
        pg += __shfl_down(pg, off, 64);
    }
    if (ln == 0) { alpha[i] = pa; beta[i] = pb; gamma[i] = pg; }
}

// ---- kernel 2: per-edge he = ef@We row, then betaE = he@b_edge ----
__global__ __launch_bounds__(256) void k_edge_proj(
    const float* __restrict__ ef, const float* __restrict__ We,
    const float* __restrict__ pve, float* __restrict__ betaE) {
    __shared__ float row[4][FE];
    const int wv = threadIdx.x >> 6, ln = threadIdx.x & 63;
    const int e = blockIdx.x * 4 + wv;
    row[wv][ln] = ef[(size_t)e * FE + ln];
    __syncthreads();
    float h = 0.f;
#pragma unroll 8
    for (int k = 0; k < FE; ++k)
        h = fmaf(row[wv][k], We[(size_t)k * FE + ln], h);
    float p = h * pve[FN + ln];
#pragma unroll
    for (int off = 32; off > 0; off >>= 1) p += __shfl_down(p, off, 64);
    if (ln == 0) betaE[e] = p;
}

// ---- kernel 3: global maxes of beta (block 0) and betaE (block 1) ----
__global__ __launch_bounds__(256) void k_maxes(
    const float* __restrict__ beta, const float* __restrict__ betaE,
    float* __restrict__ maxes) {
    const float* src = blockIdx.x == 0 ? beta : betaE;
    const int n = blockIdx.x == 0 ? N_NODES : N_EDGES;
    float m = -3.0e38f;
    for (int t = threadIdx.x; t < n; t += 256) m = fmaxf(m, src[t]);
#pragma unroll
    for (int off = 32; off > 0; off >>= 1) m = fmaxf(m, __shfl_down(m, off, 64));
    __shared__ float sm[4];
    if ((threadIdx.x & 63) == 0) sm[threadIdx.x >> 6] = m;
    __syncthreads();
    if (threadIdx.x == 0)
        maxes[blockIdx.x] = fmaxf(fmaxf(sm[0], sm[1]), fmaxf(sm[2], sm[3]));
}

// ---- kernel 4: node attention aggregation (partial over j-split) ----
__global__ __launch_bounds__(256) void k_node_att(
    const float* __restrict__ nf, const int* __restrict__ adj,
    const float* __restrict__ alpha, const float* __restrict__ beta,
    const float* __restrict__ maxes,
    float* __restrict__ accP, float* __restrict__ zP, float* __restrict__ degP) {
    __shared__ float xt[NBJ][FN];   // 16 KB
    __shared__ float wt[NBJ][NBI];  // 4 KB
    __shared__ float a_l[NBI], m_l[NBI];
    const int tid = threadIdx.x;
    const int i0 = blockIdx.x * NBI;
    const int jlen = N_NODES / NJS;
    const int j0 = blockIdx.y * jlen;
    if (tid < NBI) {
        float a = alpha[i0 + tid];
        a_l[tid] = a;
        m_l[tid] = lrelu(a + maxes[0]);
    }
    const int ti = tid >> 5;   // 0..7  : i-quad for inner loop
    const int tf = tid & 31;   // 0..31 : f-quad for inner loop
    const int mr = tid >> 3;   // 0..31 : mask row
    const int mq = tid & 7;    // 0..7  : mask i-quad
    const int xr = tid >> 5;   // 0..7  : x row base
    const int xq = tid & 31;   // 0..31 : x col quad
    float acc[4][4] = {};
    float zacc[4] = {0.f, 0.f, 0.f, 0.f};
    float dacc[4] = {0.f, 0.f, 0.f, 0.f};
    __syncthreads();
    const float a0 = a_l[mq * 4 + 0], a1 = a_l[mq * 4 + 1], a2 = a_l[mq * 4 + 2], a3 = a_l[mq * 4 + 3];
    const float q0 = m_l[mq * 4 + 0], q1 = m_l[mq * 4 + 1], q2 = m_l[mq * 4 + 2], q3 = m_l[mq * 4 + 3];

    for (int jb = j0; jb < j0 + jlen; jb += NBJ) {
        // stage X tile (32 x 128)
#pragma unroll
        for (int p = 0; p < 4; ++p) {
            float4 v = *(const float4*)(nf + (size_t)(jb + xr + 8 * p) * FN + xq * 4);
            *(float4*)&xt[xr + 8 * p][xq * 4] = v;
        }
        // stage mask tile -> w tile (32 x 32)
        {
            int4 mv = *(const int4*)(adj + (size_t)(jb + mr) * N_NODES + i0 + mq * 4);
            float bj = beta[jb + mr];
            float s0 = lrelu(a0 + bj), s1 = lrelu(a1 + bj), s2 = lrelu(a2 + bj), s3 = lrelu(a3 + bj);
            float w0 = mv.x > 0 ? __expf(s0 - q0) : 0.f;
            float w1 = mv.y > 0 ? __expf(s1 - q1) : 0.f;
            float w2 = mv.z > 0 ? __expf(s2 - q2) : 0.f;
            float w3 = mv.w > 0 ? __expf(s3 - q3) : 0.f;
            zacc[0] += w0; zacc[1] += w1; zacc[2] += w2; zacc[3] += w3;
            dacc[0] += mv.x > 0 ? 1.f : 0.f;
            dacc[1] += mv.y > 0 ? 1.f : 0.f;
            dacc[2] += mv.z > 0 ? 1.f : 0.f;
            dacc[3] += mv.w > 0 ? 1.f : 0.f;
            wt[mr][mq * 4 + 0] = w0; wt[mr][mq * 4 + 1] = w1;
            wt[mr][mq * 4 + 2] = w2; wt[mr][mq * 4 + 3] = w3;
        }
        __syncthreads();
#pragma unroll 8
        for (int jj = 0; jj < NBJ; ++jj) {
            float4 wv = *(const float4*)&wt[jj][ti * 4];
            float4 xv = *(const float4*)&xt[jj][tf * 4];
            acc[0][0] = fmaf(wv.x, xv.x, acc[0][0]);
            acc[0][1] = fmaf(wv.x, xv.y, acc[0][1]);
            acc[0][2] = fmaf(wv.x, xv.z, acc[0][2]);
            acc[0][3] = fmaf(wv.x, xv.w, acc[0][3]);
            acc[1][0] = fmaf(wv.y, xv.x, acc[1][0]);
            acc[1][1] = fmaf(wv.y, xv.y, acc[1][1]);
            acc[1][2] = fmaf(wv.y, xv.z, acc[1][2]);
            acc[1][3] = fmaf(wv.y, xv.w, acc[1][3]);
            acc[2][0] = fmaf(wv.z, xv.x, acc[2][0]);
            acc[2][1] = fmaf(wv.z, xv.y, acc[2][1]);
            acc[2][2] = fmaf(wv.z, xv.z, acc[2][2]);
            acc[2][3] = fmaf(wv.z, xv.w, acc[2][3]);
            acc[3][0] = fmaf(wv.w, xv.x, acc[3][0]);
            acc[3][1] = fmaf(wv.w, xv.y, acc[3][1]);
            acc[3][2] = fmaf(wv.w, xv.z, acc[3][2]);
            acc[3][3] = fmaf(wv.w, xv.w, acc[3][3]);
        }
        __syncthreads();
    }
    // deterministic z/deg reduction reusing wt
    wt[mr][mq * 4 + 0] = zacc[0]; wt[mr][mq * 4 + 1] = zacc[1];
    wt[mr][mq * 4 + 2] = zacc[2]; wt[mr][mq * 4 + 3] = zacc[3];
    __syncthreads();
    float zsum = 0.f;
    if (tid < NBI) {
#pragma unroll 8
        for (int r = 0; r < NBJ; ++r) zsum += wt[r][tid];
    }
    __syncthreads();
    wt[mr][mq * 4 + 0] = dacc[0]; wt[mr][mq * 4 + 1] = dacc[1];
    wt[mr][mq * 4 + 2] = dacc[2]; wt[mr][mq * 4 + 3] = dacc[3];
    __syncthreads();
    if (tid < NBI) {
        float dsum = 0.f;
#pragma unroll 8
        for (int r = 0; r < NBJ; ++r) dsum += wt[r][tid];
        zP[blockIdx.y * N_NODES + i0 + tid] = zsum;
        degP[blockIdx.y * N_NODES + i0 + tid] = dsum;
    }
    // write acc partials
#pragma unroll
    for (int ii = 0; ii < 4; ++ii) {
        int i = i0 + ti * 4 + ii;
        *(float4*)(accP + ((size_t)blockIdx.y * N_NODES + i) * FN + tf * 4) =
            make_float4(acc[ii][0], acc[ii][1], acc[ii][2], acc[ii][3]);
    }
}

// ---- kernel 5: edge attention aggregation (partial over j-split) ----
__global__ __launch_bounds__(256) void k_edge_att(
    const float* __restrict__ ef, const int* __restrict__ eadj,
    const float* __restrict__ gamma, const float* __restrict__ betaE,
    const float* __restrict__ maxes,
    float* __restrict__ accP, float* __restrict__ zP, float* __restrict__ degP) {
    __shared__ float xt[EBJ][FE];   // 8 KB
    __shared__ float wt[EBJ][EBI];  // 8 KB
    __shared__ float a_l[EBI], m_l[EBI];
    const int tid = threadIdx.x;
    const int i0 = blockIdx.x * EBI;
    const int jlen = N_EDGES / EJS;
    const int j0 = blockIdx.y * jlen;
    if (tid < EBI) {
        float a = gamma[i0 + tid];
        a_l[tid] = a;
        m_l[tid] = lrelu(a + maxes[1]);
    }
    const int ti = tid >> 4;   // 0..15 : i-quad
    const int tf = tid & 15;   // 0..15 : f-quad
    const int mr = tid >> 4;   // 0..15 : row base (rows mr, mr+16)
    const int mq = tid & 15;   // 0..15 : i-quad for mask
    float acc[4][4] = {};
    float zacc[4] = {0.f, 0.f, 0.f, 0.f};
    float dacc[4] = {0.f, 0.f, 0.f, 0.f};
    __syncthreads();
    const float a0 = a_l[mq * 4 + 0], a1 = a_l[mq * 4 + 1], a2 = a_l[mq * 4 + 2], a3 = a_l[mq * 4 + 3];
    const float q0 = m_l[mq * 4 + 0], q1 = m_l[mq * 4 + 1], q2 = m_l[mq * 4 + 2], q3 = m_l[mq * 4 + 3];

    for (int jb = j0; jb < j0 + jlen; jb += EBJ) {
        // stage X tile (32 x 64)
#pragma unroll
        for (int p = 0; p < 2; ++p) {
            float4 v = *(const float4*)(ef + (size_t)(jb + mr + 16 * p) * FE + mq * 4);
            *(float4*)&xt[mr + 16 * p][mq * 4] = v;
        }
        // stage mask -> w tile (32 x 64)
#pragma unroll
        for (int p = 0; p < 2; ++p) {
            int r = mr + 16 * p;
            int4 mv = *(const int4*)(eadj + (size_t)(jb + r) * N_NODES + i0 + mq * 4);
            float bj = betaE[jb + r];
            float s0 = lrelu(a0 + bj), s1 = lrelu(a1 + bj), s2 = lrelu(a2 + bj), s3 = lrelu(a3 + bj);
            float w0 = mv.x > 0 ? __expf(s0 - q0) : 0.f;
            float w1 = mv.y > 0 ? __expf(s1 - q1) : 0.f;
            float w2 = mv.z > 0 ? __expf(s2 - q2) : 0.f;
            float w3 = mv.w > 0 ? __expf(s3 - q3) : 0.f;
            zacc[0] += w0; zacc[1] += w1; zacc[2] += w2; zacc[3] += w3;
            dacc[0] += mv.x > 0 ? 1.f : 0.f;
            dacc[1] += mv.y > 0 ? 1.f : 0.f;
            dacc[2] += mv.z > 0 ? 1.f : 0.f;
            dacc[3] += mv.w > 0 ? 1.f : 0.f;
            wt[r][mq * 4 + 0] = w0; wt[r][mq * 4 + 1] = w1;
            wt[r][mq * 4 + 2] = w2; wt[r][mq * 4 + 3] = w3;
        }
        __syncthreads();
#pragma unroll 8
        for (int jj = 0; jj < EBJ; ++jj) {
            float4 wv = *(const float4*)&wt[jj][ti * 4];
            float4 xv = *(const float4*)&xt[jj][tf * 4];
            acc[0][0] = fmaf(wv.x, xv.x, acc[0][0]);
            acc[0][1] = fmaf(wv.x, xv.y, acc[0][1]);
            acc[0][2] = fmaf(wv.x, xv.z, acc[0][2]);
            acc[0][3] = fmaf(wv.x, xv.w, acc[0][3]);
            acc[1][0] = fmaf(wv.y, xv.x, acc[1][0]);
            acc[1][1] = fmaf(wv.y, xv.y, acc[1][1]);
            acc[1][2] = fmaf(wv.y, xv.z, acc[1][2]);
            acc[1][3] = fmaf(wv.y, xv.w, acc[1][3]);
            acc[2][0] = fmaf(wv.z, xv.x, acc[2][0]);
            acc[2][1] = fmaf(wv.z, xv.y, acc[2][1]);
            acc[2][2] = fmaf(wv.z, xv.z, acc[2][2]);
            acc[2][3] = fmaf(wv.z, xv.w, acc[2][3]);
            acc[3][0] = fmaf(wv.w, xv.x, acc[3][0]);
            acc[3][1] = fmaf(wv.w, xv.y, acc[3][1]);
            acc[3][2] = fmaf(wv.w, xv.z, acc[3][2]);
            acc[3][3] = fmaf(wv.w, xv.w, acc[3][3]);
        }
        __syncthreads();
    }
    // deterministic z/deg reduction (only rows 0..15 of wt used)
    wt[mr][mq * 4 + 0] = zacc[0]; wt[mr][mq * 4 + 1] = zacc[1];
    wt[mr][mq * 4 + 2] = zacc[2]; wt[mr][mq * 4 + 3] = zacc[3];
    __syncthreads();
    float zsum = 0.f;
    if (tid < EBI) {
#pragma unroll 8
        for (int r = 0; r < 16; ++r) zsum += wt[r][tid];
    }
    __syncthreads();
    wt[mr][mq * 4 + 0] = dacc[0]; wt[mr][mq * 4 + 1] = dacc[1];
    wt[mr][mq * 4 + 2] = dacc[2]; wt[mr][mq * 4 + 3] = dacc[3];
    __syncthreads();
    if (tid < EBI) {
        float dsum = 0.f;
#pragma unroll 8
        for (int r = 0; r < 16; ++r) dsum += wt[r][tid];
        zP[blockIdx.y * N_NODES + i0 + tid] = zsum;
        degP[blockIdx.y * N_NODES + i0 + tid] = dsum;
    }
#pragma unroll
    for (int ii = 0; ii < 4; ++ii) {
        int i = i0 + ti * 4 + ii;
        *(float4*)(accP + ((size_t)blockIdx.y * N_NODES + i) * FE + tf * 4) =
            make_float4(acc[ii][0], acc[ii][1], acc[ii][2], acc[ii][3]);
    }
}

// ---- kernel 6: node epilogue: combine partials, means, @Wn, lrelu, write cols 0..127 ----
__global__ __launch_bounds__(256) void k_node_out(
    const float* __restrict__ accP, const float* __restrict__ zP,
    const float* __restrict__ degP, const float* __restrict__ Wn,
    float* __restrict__ out) {
    __shared__ float ml[4][FN];
    const int wv = threadIdx.x >> 6, ln = threadIdx.x & 63;
    const int i = blockIdx.x * 4 + wv;
    float s0 = 0.f, s1 = 0.f;
#pragma unroll
    for (int js = 0; js < NJS; ++js) {
        float2 v = *(const float2*)(accP + ((size_t)js * N_NODES + i) * FN + ln * 2);
        s0 += v.x; s1 += v.y;
    }
    float z = 0.f, d = 0.f;
#pragma unroll
    for (int js = 0; js < NJS; ++js) { z += zP[js * N_NODES + i]; d += degP[js * N_NODES + i]; }
    float zd = z * d;
    float inv = zd > 0.f ? 1.f / zd : 0.f;
    ml[wv][ln * 2] = s0 * inv; ml[wv][ln * 2 + 1] = s1 * inv;
    __syncthreads();
    float o0 = 0.f, o1 = 0.f;
#pragma unroll 8
    for (int k = 0; k < FN; ++k) {
        float mvv = ml[wv][k];
        float2 w2 = *(const float2*)(Wn + (size_t)k * FN + ln * 2);
        o0 = fmaf(mvv, w2.x, o0); o1 = fmaf(mvv, w2.y, o1);
    }
    out[(size_t)i * 192 + ln * 2] = lrelu(o0);
    out[(size_t)i * 192 + ln * 2 + 1] = lrelu(o1);
}

// ---- kernel 7: edge epilogue: combine partials, means, @We, lrelu, write cols 128..191 ----
__global__ __launch_bounds__(256) void k_edge_out(
    const float* __restrict__ accP, const float* __restrict__ zP,
    const float* __restrict__ degP, const float* __restrict__ We,
    float* __restrict__ out) {
    __shared__ float ml[4][FE];
    const int wv = threadIdx.x >> 6, ln = threadIdx.x & 63;
    const int i = blockIdx.x * 4 + wv;
    float s = 0.f;
#pragma unroll
    for (int js = 0; js < EJS; ++js)
        s += accP[((size_t)js * N_NODES + i) * FE + ln];
    float z = 0.f, d = 0.f;
#pragma unroll
    for (int js = 0; js < EJS; ++js) { z += zP[js * N_NODES + i]; d += degP[js * N_NODES + i]; }
    float zd = z * d;
    float inv = zd > 0.f ? 1.f / zd : 0.f;
    ml[wv][ln] = s * inv;
    __syncthreads();
    float o = 0.f;
#pragma unroll 8
    for (int k = 0; k < FE; ++k)
        o = fmaf(ml[wv][k], We[(size_t)k * FE + ln], o);
    out[(size_t)i * 192 + 128 + ln] = lrelu(o);
}

extern "C" void kernel_launch(void* const* d_in, const int* in_sizes, int n_in,
                              void* d_out, int out_size, void* d_ws, size_t ws_size,
                              hipStream_t stream) {
    const float* nf   = (const float*)d_in[0];
    const float* ef   = (const float*)d_in[1];
    const int*   adj  = (const int*)d_in[2];
    const int*   eadj = (const int*)d_in[3];
    const float* Wn   = (const float*)d_in[4];
    const float* We   = (const float*)d_in[5];
    const float* pvn  = (const float*)d_in[6];
    const float* pve  = (const float*)d_in[7];
    float* out = (float*)d_out;
    float* ws  = (float*)d_ws;

    float* alpha = ws;                    // 4096
    float* beta  = ws + 4096;             // 4096
    float* gamma = ws + 8192;             // 4096
    float* betaE = ws + 12288;            // 16384
    float* maxes = ws + 28672;            // 2 (padded)
    float* accN  = ws + 32768;            // 8 * 4096 * 128
    float* zN    = accN + (size_t)NJS * N_NODES * FN;   // 8*4096
    float* degN  = zN + NJS * N_NODES;                  // 8*4096
    float* accE  = degN + NJS * N_NODES;                // 16 * 4096 * 64
    float* zE    = accE + (size_t)EJS * N_NODES * FE;   // 16*4096
    float* degE  = zE + EJS * N_NODES;                  // 16*4096

    k_node_proj<<<N_NODES / 4, 256, 0, stream>>>(nf, Wn, pvn, pve, alpha, beta, gamma);
    k_edge_proj<<<N_EDGES / 4, 256, 0, stream>>>(ef, We, pve, betaE);
    k_maxes<<<2, 256, 0, stream>>>(beta, betaE, maxes);
    k_node_att<<<dim3(N_NODES / NBI, NJS), 256, 0, stream>>>(nf, adj, alpha, beta, maxes, accN, zN, degN);
    k_edge_att<<<dim3(N_NODES / EBI, EJS), 256, 0, stream>>>(ef, eadj, gamma, betaE, maxes, accE, zE, degE);
    k_node_out<<<N_NODES / 4, 256, 0, stream>>>(accN, zN, degN, Wn, out);
    k_edge_out<<<N_NODES / 4, 256, 0, stream>>>(accE, zE, degE, We, out);
}

// Round 2
// 165.442 us; speedup vs baseline: 1.7456x; 1.7456x over previous
//
#include <hip/hip_runtime.h>

typedef short bf16x8 __attribute__((ext_vector_type(8)));
typedef float f32x4 __attribute__((ext_vector_type(4)));

#define N_NODES 4096
#define N_EDGES 16384
#define FN 128
#define FE 64
#define NJS 8
#define EJS 16

__device__ __forceinline__ float lrelu(float x) { return x >= 0.f ? x : 0.01f * x; }
// float -> bf16 round-to-nearest-even (finite inputs only)
__device__ __forceinline__ unsigned short f2bf(float f) {
    unsigned int x = __float_as_uint(f);
    return (unsigned short)((x + 0x7fffu + ((x >> 16) & 1u)) >> 16);
}

// ---- kernel 1: per-node h = nf@Wn row, then alpha/beta/gamma dots (h never stored) ----
__global__ __launch_bounds__(256) void k_node_proj(
    const float* __restrict__ nf, const float* __restrict__ Wn,
    const float* __restrict__ pvn, const float* __restrict__ pve,
    float* __restrict__ alpha, float* __restrict__ beta, float* __restrict__ gamma) {
    __shared__ float row[4][FN];
    const int wv = threadIdx.x >> 6, ln = threadIdx.x & 63;
    const int i = blockIdx.x * 4 + wv;
    float2 r2 = *(const float2*)(nf + (size_t)i * FN + ln * 2);
    row[wv][ln * 2] = r2.x; row[wv][ln * 2 + 1] = r2.y;
    __syncthreads();
    float h0 = 0.f, h1 = 0.f;
#pragma unroll 8
    for (int k = 0; k < FN; ++k) {
        float nv = row[wv][k];
        float2 w2 = *(const float2*)(Wn + (size_t)k * FN + ln * 2);
        h0 = fmaf(nv, w2.x, h0); h1 = fmaf(nv, w2.y, h1);
    }
    float2 as = *(const float2*)(pvn + ln * 2);
    float2 an = *(const float2*)(pvn + FN + ln * 2);
    float2 bs = *(const float2*)(pve + ln * 2);
    float pa = h0 * as.x + h1 * as.y;
    float pb = h0 * an.x + h1 * an.y;
    float pg = h0 * bs.x + h1 * bs.y;
#pragma unroll
    for (int off = 32; off > 0; off >>= 1) {
        pa += __shfl_down(pa, off, 64);
        pb += __shfl_down(pb, off, 64);
        pg += __shfl_down(pg, off, 64);
    }
    if (ln == 0) { alpha[i] = pa; beta[i] = pb; gamma[i] = pg; }
}

// ---- kernel 2: per-edge he = ef@We row, then betaE = he@b_edge ----
__global__ __launch_bounds__(256) void k_edge_proj(
    const float* __restrict__ ef, const float* __restrict__ We,
    const float* __restrict__ pve, float* __restrict__ betaE) {
    __shared__ float row[4][FE];
    const int wv = threadIdx.x >> 6, ln = threadIdx.x & 63;
    const int e = blockIdx.x * 4 + wv;
    row[wv][ln] = ef[(size_t)e * FE + ln];
    __syncthreads();
    float h = 0.f;
#pragma unroll 8
    for (int k = 0; k < FE; ++k)
        h = fmaf(row[wv][k], We[(size_t)k * FE + ln], h);
    float p = h * pve[FN + ln];
#pragma unroll
    for (int off = 32; off > 0; off >>= 1) p += __shfl_down(p, off, 64);
    if (ln == 0) betaE[e] = p;
}

// ---- kernel 3: global maxes of beta (block 0) and betaE (block 1) ----
__global__ __launch_bounds__(256) void k_maxes(
    const float* __restrict__ beta, const float* __restrict__ betaE,
    float* __restrict__ maxes) {
    const float* src = blockIdx.x == 0 ? beta : betaE;
    const int n = blockIdx.x == 0 ? N_NODES : N_EDGES;
    float m = -3.0e38f;
    for (int t = threadIdx.x; t < n; t += 256) m = fmaxf(m, src[t]);
#pragma unroll
    for (int off = 32; off > 0; off >>= 1) m = fmaxf(m, __shfl_down(m, off, 64));
    __shared__ float sm[4];
    if ((threadIdx.x & 63) == 0) sm[threadIdx.x >> 6] = m;
    __syncthreads();
    if (threadIdx.x == 0)
        maxes[blockIdx.x] = fmaxf(fmaxf(sm[0], sm[1]), fmaxf(sm[2], sm[3]));
}

// ---- kernel 4: transpose + bf16 convert: src[J][F] f32 -> dst[F][J] bf16 ----
__global__ __launch_bounds__(256) void k_prep(
    const float* __restrict__ src, unsigned short* __restrict__ dst,
    const int J, const int F) {
    __shared__ float tile[64][65];
    const int t = threadIdx.x;
    const int j0 = blockIdx.x * 64, f0 = blockIdx.y * 64;
#pragma unroll
    for (int p = 0; p < 4; ++p) {
        int j = (t >> 4) + p * 16;
        float4 v = *(const float4*)(src + (size_t)(j0 + j) * F + f0 + (t & 15) * 4);
        tile[j][(t & 15) * 4 + 0] = v.x;
        tile[j][(t & 15) * 4 + 1] = v.y;
        tile[j][(t & 15) * 4 + 2] = v.z;
        tile[j][(t & 15) * 4 + 3] = v.w;
    }
    __syncthreads();
#pragma unroll
    for (int p = 0; p < 2; ++p) {
        int f = (t >> 3) + p * 32;
        int c = t & 7;
        bf16x8 v;
#pragma unroll
        for (int e = 0; e < 8; ++e) v[e] = (short)f2bf(tile[c * 8 + e][f]);
        *(bf16x8*)(dst + (size_t)(f0 + f) * J + j0 + c * 8) = v;
    }
}

// ---- kernel 5: node attention aggregation, MFMA (i-block 32, f=128, kstep 64) ----
__global__ __launch_bounds__(256) void k_node_att(
    const unsigned short* __restrict__ Xt,   // [128][4096] bf16
    const int* __restrict__ adj,
    const float* __restrict__ alpha, const float* __restrict__ beta,
    const float* __restrict__ maxes,
    float* __restrict__ accP, float* __restrict__ zP, float* __restrict__ degP) {
    __shared__ unsigned short xlds[128 * 64];  // A tiles, swizzled: 16 KB
    __shared__ unsigned short wlds[4 * 512];   // B frags [kb*2+nb][lane*8]: 4 KB
    __shared__ float bb[512];
    __shared__ float zred[8][32];
    __shared__ float dred[8][32];
    const int t = threadIdx.x;
    const int i0 = blockIdx.x * 32;
    const int bj = blockIdx.y;
    const int j0 = bj * (N_NODES / NJS);       // 512 j per block
    const int il = t & 31;
    const int jg = t >> 5;                     // 0..7
    const float a_i = alpha[i0 + il];
    const float m_i = lrelu(a_i + maxes[0]);
    if (t < 128) *(float4*)&bb[t * 4] = *(const float4*)(beta + j0 + t * 4);
    const int l = t & 63, wid = t >> 6;
    const int wm = wid >> 1, wn = wid & 1;
    const int l15 = l & 15, l4 = l >> 4;
    const int sf = t >> 3, sc = t & 7;         // Xt stage: rows sf+32p, chunk sc
    const int xswz = (sc ^ (sf & 7)) * 8;      // (sf+32p)&7 == sf&7
    const int wdst = ((jg >> 2) * 2 + (il >> 4)) * 512 + ((il & 15) + 16 * (jg & 3)) * 8;
    f32x4 acc[4] = {{0,0,0,0},{0,0,0,0},{0,0,0,0},{0,0,0,0}};
    float zacc = 0.f, dacc = 0.f;
    __syncthreads();
    for (int ks = 0; ks < 8; ++ks) {
        const int jb = ks * 64;
        const int* mp = adj + (size_t)(j0 + jb + jg * 8) * N_NODES + i0 + il;
        int mk[8];
#pragma unroll
        for (int e = 0; e < 8; ++e) mk[e] = mp[(size_t)e * N_NODES];
        const unsigned short* xs = Xt + (size_t)sf * N_NODES + j0 + jb + sc * 8;
        bf16x8 xv0 = *(const bf16x8*)(xs);
        bf16x8 xv1 = *(const bf16x8*)(xs + (size_t)32 * N_NODES);
        bf16x8 xv2 = *(const bf16x8*)(xs + (size_t)64 * N_NODES);
        bf16x8 xv3 = *(const bf16x8*)(xs + (size_t)96 * N_NODES);
        bf16x8 wfrag;
#pragma unroll
        for (int e = 0; e < 8; ++e) {
            float s = lrelu(a_i + bb[jb + jg * 8 + e]);
            float w = mk[e] > 0 ? __expf(s - m_i) : 0.f;
            zacc += w;
            dacc += (mk[e] > 0) ? 1.f : 0.f;
            wfrag[e] = (short)f2bf(w);
        }
        __syncthreads();
        *(bf16x8*)&xlds[(sf +  0) * 64 + xswz] = xv0;
        *(bf16x8*)&xlds[(sf + 32) * 64 + xswz] = xv1;
        *(bf16x8*)&xlds[(sf + 64) * 64 + xswz] = xv2;
        *(bf16x8*)&xlds[(sf + 96) * 64 + xswz] = xv3;
        *(bf16x8*)&wlds[wdst] = wfrag;
        __syncthreads();
#pragma unroll
        for (int kb = 0; kb < 2; ++kb) {
            bf16x8 b = *(const bf16x8*)&wlds[(kb * 2 + wn) * 512 + l * 8];
#pragma unroll
            for (int mi = 0; mi < 4; ++mi) {
                const int fr = wm * 64 + mi * 16 + l15;
                bf16x8 a = *(const bf16x8*)&xlds[fr * 64 + (((kb * 4 + l4) ^ (fr & 7)) * 8)];
                acc[mi] = __builtin_amdgcn_mfma_f32_16x16x32_bf16(a, b, acc[mi], 0, 0, 0);
            }
        }
    }
    zred[jg][il] = zacc;
    dred[jg][il] = dacc;
    __syncthreads();
    if (t < 32) {
        float z = 0.f, d = 0.f;
#pragma unroll
        for (int g = 0; g < 8; ++g) { z += zred[g][t]; d += dred[g][t]; }
        zP[bj * N_NODES + i0 + t] = z;
        degP[bj * N_NODES + i0 + t] = d;
    }
    const int ig = i0 + wn * 16 + l15;
#pragma unroll
    for (int mi = 0; mi < 4; ++mi) {
        const int fg = wm * 64 + mi * 16 + l4 * 4;
        *(f32x4*)(accP + ((size_t)bj * N_NODES + ig) * FN + fg) = acc[mi];
    }
}

// ---- kernel 6: edge attention aggregation, MFMA (i-block 64, f=64, kstep 32) ----
__global__ __launch_bounds__(256) void k_edge_att(
    const unsigned short* __restrict__ Xt,   // [64][16384] bf16
    const int* __restrict__ eadj,
    const float* __restrict__ gamma, const float* __restrict__ betaE,
    const float* __restrict__ maxes,
    float* __restrict__ accP, float* __restrict__ zP, float* __restrict__ degP) {
    __shared__ unsigned short xlds[64 * 32];   // 4 KB
    __shared__ unsigned short wlds[4 * 512];   // [nb][lane*8]: 4 KB
    __shared__ float bb[1024];
    __shared__ float zred[4][64];
    __shared__ float dred[4][64];
    const int t = threadIdx.x;
    const int i0 = blockIdx.x * 64;
    const int bj = blockIdx.y;
    const int j0 = bj * (N_EDGES / EJS);       // 1024 j per block
    const int il = t & 63;
    const int jg = t >> 6;                     // 0..3 (wave-uniform)
    const float g_i = gamma[i0 + il];
    const float m_i = lrelu(g_i + maxes[1]);
    *(float4*)&bb[t * 4] = *(const float4*)(betaE + j0 + t * 4);
    const int l = t & 63, wid = t >> 6;
    const int wm = wid >> 1, wn = wid & 1;
    const int l15 = l & 15, l4 = l >> 4;
    const int sf = t >> 2, sc = t & 3;
    const unsigned short* xsrc = Xt + (size_t)sf * N_EDGES + j0 + sc * 8;
    const int xdst = sf * 32 + ((sc ^ (sf & 3)) * 8);
    const int wdst = (il >> 4) * 512 + ((il & 15) + 16 * jg) * 8;
    const int ar0 = (wm * 2) * 16 + l15;
    const int ar1 = (wm * 2 + 1) * 16 + l15;
    const int aad0 = ar0 * 32 + ((l4 ^ (ar0 & 3)) * 8);
    const int aad1 = ar1 * 32 + ((l4 ^ (ar1 & 3)) * 8);
    const int bad0 = (wn * 2) * 512 + l * 8;
    const int bad1 = (wn * 2 + 1) * 512 + l * 8;
    f32x4 acc00 = {0,0,0,0}, acc01 = {0,0,0,0}, acc10 = {0,0,0,0}, acc11 = {0,0,0,0};
    float zacc = 0.f, dacc = 0.f;
    __syncthreads();
    for (int ks = 0; ks < 32; ++ks) {
        const int jb = ks * 32;
        const int* mp = eadj + (size_t)(j0 + jb + jg * 8) * N_NODES + i0 + il;
        int mk[8];
#pragma unroll
        for (int e = 0; e < 8; ++e) mk[e] = mp[(size_t)e * N_NODES];
        bf16x8 xv = *(const bf16x8*)(xsrc + jb);
        bf16x8 wfrag;
#pragma unroll
        for (int e = 0; e < 8; ++e) {
            float s = lrelu(g_i + bb[jb + jg * 8 + e]);
            float w = mk[e] > 0 ? __expf(s - m_i) : 0.f;
            zacc += w;
            dacc += (mk[e] > 0) ? 1.f : 0.f;
            wfrag[e] = (short)f2bf(w);
        }
        __syncthreads();
        *(bf16x8*)&xlds[xdst] = xv;
        *(bf16x8*)&wlds[wdst] = wfrag;
        __syncthreads();
        bf16x8 a0 = *(const bf16x8*)&xlds[aad0];
        bf16x8 a1 = *(const bf16x8*)&xlds[aad1];
        bf16x8 b0 = *(const bf16x8*)&wlds[bad0];
        bf16x8 b1 = *(const bf16x8*)&wlds[bad1];
        acc00 = __builtin_amdgcn_mfma_f32_16x16x32_bf16(a0, b0, acc00, 0, 0, 0);
        acc01 = __builtin_amdgcn_mfma_f32_16x16x32_bf16(a0, b1, acc01, 0, 0, 0);
        acc10 = __builtin_amdgcn_mfma_f32_16x16x32_bf16(a1, b0, acc10, 0, 0, 0);
        acc11 = __builtin_amdgcn_mfma_f32_16x16x32_bf16(a1, b1, acc11, 0, 0, 0);
    }
    zred[jg][il] = zacc;
    dred[jg][il] = dacc;
    __syncthreads();
    if (t < 64) {
        float z = zred[0][t] + zred[1][t] + zred[2][t] + zred[3][t];
        float d = dred[0][t] + dred[1][t] + dred[2][t] + dred[3][t];
        zP[bj * N_NODES + i0 + t] = z;
        degP[bj * N_NODES + i0 + t] = d;
    }
    const size_t obase = (size_t)bj * N_NODES;
    {
        int ig0 = i0 + (wn * 2) * 16 + l15;
        int ig1 = i0 + (wn * 2 + 1) * 16 + l15;
        int fg0 = (wm * 2) * 16 + l4 * 4;
        int fg1 = (wm * 2 + 1) * 16 + l4 * 4;
        *(f32x4*)(accP + (obase + ig0) * FE + fg0) = acc00;
        *(f32x4*)(accP + (obase + ig1) * FE + fg0) = acc01;
        *(f32x4*)(accP + (obase + ig0) * FE + fg1) = acc10;
        *(f32x4*)(accP + (obase + ig1) * FE + fg1) = acc11;
    }
}

// ---- kernel 7: node epilogue ----
__global__ __launch_bounds__(256) void k_node_out(
    const float* __restrict__ accP, const float* __restrict__ zP,
    const float* __restrict__ degP, const float* __restrict__ Wn,
    float* __restrict__ out) {
    __shared__ float ml[4][FN];
    const int wv = threadIdx.x >> 6, ln = threadIdx.x & 63;
    const int i = blockIdx.x * 4 + wv;
    float s0 = 0.f, s1 = 0.f;
#pragma unroll
    for (int js = 0; js < NJS; ++js) {
        float2 v = *(const float2*)(accP + ((size_t)js * N_NODES + i) * FN + ln * 2);
        s0 += v.x; s1 += v.y;
    }
    float z = 0.f, d = 0.f;
#pragma unroll
    for (int js = 0; js < NJS; ++js) { z += zP[js * N_NODES + i]; d += degP[js * N_NODES + i]; }
    float zd = z * d;
    float inv = zd > 0.f ? 1.f / zd : 0.f;
    ml[wv][ln * 2] = s0 * inv; ml[wv][ln * 2 + 1] = s1 * inv;
    __syncthreads();
    float o0 = 0.f, o1 = 0.f;
#pragma unroll 8
    for (int k = 0; k < FN; ++k) {
        float mvv = ml[wv][k];
        float2 w2 = *(const float2*)(Wn + (size_t)k * FN + ln * 2);
        o0 = fmaf(mvv, w2.x, o0); o1 = fmaf(mvv, w2.y, o1);
    }
    out[(size_t)i * 192 + ln * 2] = lrelu(o0);
    out[(size_t)i * 192 + ln * 2 + 1] = lrelu(o1);
}

// ---- kernel 8: edge epilogue ----
__global__ __launch_bounds__(256) void k_edge_out(
    const float* __restrict__ accP, const float* __restrict__ zP,
    const float* __restrict__ degP, const float* __restrict__ We,
    float* __restrict__ out) {
    __shared__ float ml[4][FE];
    const int wv = threadIdx.x >> 6, ln = threadIdx.x & 63;
    const int i = blockIdx.x * 4 + wv;
    float s = 0.f;
#pragma unroll
    for (int js = 0; js < EJS; ++js)
        s += accP[((size_t)js * N_NODES + i) * FE + ln];
    float z = 0.f, d = 0.f;
#pragma unroll
    for (int js = 0; js < EJS; ++js) { z += zP[js * N_NODES + i]; d += degP[js * N_NODES + i]; }
    float zd = z * d;
    float inv = zd > 0.f ? 1.f / zd : 0.f;
    ml[wv][ln] = s * inv;
    __syncthreads();
    float o = 0.f;
#pragma unroll 8
    for (int k = 0; k < FE; ++k)
        o = fmaf(ml[wv][k], We[(size_t)k * FE + ln], o);
    out[(size_t)i * 192 + 128 + ln] = lrelu(o);
}

extern "C" void kernel_launch(void* const* d_in, const int* in_sizes, int n_in,
                              void* d_out, int out_size, void* d_ws, size_t ws_size,
                              hipStream_t stream) {
    (void)in_sizes; (void)n_in; (void)out_size; (void)ws_size;
    const float* nf   = (const float*)d_in[0];
    const float* ef   = (const float*)d_in[1];
    const int*   adj  = (const int*)d_in[2];
    const int*   eadj = (const int*)d_in[3];
    const float* Wn   = (const float*)d_in[4];
    const float* We   = (const float*)d_in[5];
    const float* pvn  = (const float*)d_in[6];
    const float* pve  = (const float*)d_in[7];
    float* out = (float*)d_out;

    float* alpha = (float*)d_ws;                       // 4096
    float* beta  = alpha + 4096;                       // 4096
    float* gamma = beta + 4096;                        // 4096
    float* betaE = gamma + 4096;                       // 16384
    float* maxes = betaE + 16384;                      // 64 (padded)
    unsigned short* XtN = (unsigned short*)(maxes + 64);          // 128*4096 bf16
    unsigned short* XtE = XtN + (size_t)FN * N_NODES;             // 64*16384 bf16
    float* accN = (float*)(XtE + (size_t)FE * N_EDGES);           // NJS*4096*128
    float* zN   = accN + (size_t)NJS * N_NODES * FN;
    float* degN = zN + (size_t)NJS * N_NODES;
    float* accE = degN + (size_t)NJS * N_NODES;                   // EJS*4096*64
    float* zE   = accE + (size_t)EJS * N_NODES * FE;
    float* degE = zE + (size_t)EJS * N_NODES;

    k_node_proj<<<N_NODES / 4, 256, 0, stream>>>(nf, Wn, pvn, pve, alpha, beta, gamma);
    k_edge_proj<<<N_EDGES / 4, 256, 0, stream>>>(ef, We, pve, betaE);
    k_maxes<<<2, 256, 0, stream>>>(beta, betaE, maxes);
    k_prep<<<dim3(N_NODES / 64, FN / 64), 256, 0, stream>>>(nf, XtN, N_NODES, FN);
    k_prep<<<dim3(N_EDGES / 64, FE / 64), 256, 0, stream>>>(ef, XtE, N_EDGES, FE);
    k_node_att<<<dim3(N_NODES / 32, NJS), 256, 0, stream>>>(XtN, adj, alpha, beta, maxes, accN, zN, degN);
    k_edge_att<<<dim3(N_NODES / 64, EJS), 256, 0, stream>>>(XtE, eadj, gamma, betaE, maxes, accE, zE, degE);
    k_node_out<<<N_NODES / 4, 256, 0, stream>>>(accN, zN, degN, Wn, out);
    k_edge_out<<<N_NODES / 4, 256, 0, stream>>>(accE, zE, degE, We, out);
}

// Round 3
// 165.057 us; speedup vs baseline: 1.7497x; 1.0023x over previous
//
#include <hip/hip_runtime.h>

typedef short bf16x8 __attribute__((ext_vector_type(8)));
typedef float f32x4 __attribute__((ext_vector_type(4)));

#define N_NODES 4096
#define N_EDGES 16384
#define FN 128
#define FE 64
#define NJS 8
#define EJS 16

__device__ __forceinline__ float lrelu(float x) { return x >= 0.f ? x : 0.01f * x; }
// float -> bf16 round-to-nearest-even (finite inputs only)
__device__ __forceinline__ unsigned short f2bf(float f) {
    unsigned int x = __float_as_uint(f);
    return (unsigned short)((x + 0x7fffu + ((x >> 16) & 1u)) >> 16);
}

// ---- kernel 1: per-node h = nf@Wn row, then alpha/beta/gamma dots (h never stored) ----
__global__ __launch_bounds__(256) void k_node_proj(
    const float* __restrict__ nf, const float* __restrict__ Wn,
    const float* __restrict__ pvn, const float* __restrict__ pve,
    float* __restrict__ alpha, float* __restrict__ beta, float* __restrict__ gamma) {
    __shared__ float row[4][FN];
    const int wv = threadIdx.x >> 6, ln = threadIdx.x & 63;
    const int i = blockIdx.x * 4 + wv;
    float2 r2 = *(const float2*)(nf + (size_t)i * FN + ln * 2);
    row[wv][ln * 2] = r2.x; row[wv][ln * 2 + 1] = r2.y;
    __syncthreads();
    float h0 = 0.f, h1 = 0.f;
#pragma unroll 8
    for (int k = 0; k < FN; ++k) {
        float nv = row[wv][k];
        float2 w2 = *(const float2*)(Wn + (size_t)k * FN + ln * 2);
        h0 = fmaf(nv, w2.x, h0); h1 = fmaf(nv, w2.y, h1);
    }
    float2 as = *(const float2*)(pvn + ln * 2);
    float2 an = *(const float2*)(pvn + FN + ln * 2);
    float2 bs = *(const float2*)(pve + ln * 2);
    float pa = h0 * as.x + h1 * as.y;
    float pb = h0 * an.x + h1 * an.y;
    float pg = h0 * bs.x + h1 * bs.y;
#pragma unroll
    for (int off = 32; off > 0; off >>= 1) {
        pa += __shfl_down(pa, off, 64);
        pb += __shfl_down(pb, off, 64);
        pg += __shfl_down(pg, off, 64);
    }
    if (ln == 0) { alpha[i] = pa; beta[i] = pb; gamma[i] = pg; }
}

// ---- kernel 2: per-edge he = ef@We row, then betaE = he@b_edge ----
__global__ __launch_bounds__(256) void k_edge_proj(
    const float* __restrict__ ef, const float* __restrict__ We,
    const float* __restrict__ pve, float* __restrict__ betaE) {
    __shared__ float row[4][FE];
    const int wv = threadIdx.x >> 6, ln = threadIdx.x & 63;
    const int e = blockIdx.x * 4 + wv;
    row[wv][ln] = ef[(size_t)e * FE + ln];
    __syncthreads();
    float h = 0.f;
#pragma unroll 8
    for (int k = 0; k < FE; ++k)
        h = fmaf(row[wv][k], We[(size_t)k * FE + ln], h);
    float p = h * pve[FN + ln];
#pragma unroll
    for (int off = 32; off > 0; off >>= 1) p += __shfl_down(p, off, 64);
    if (ln == 0) betaE[e] = p;
}

// ---- kernel 3: global maxes of beta (block 0) and betaE (block 1) ----
__global__ __launch_bounds__(256) void k_maxes(
    const float* __restrict__ beta, const float* __restrict__ betaE,
    float* __restrict__ maxes) {
    const float* src = blockIdx.x == 0 ? beta : betaE;
    const int n = blockIdx.x == 0 ? N_NODES : N_EDGES;
    float m = -3.0e38f;
    for (int t = threadIdx.x; t < n; t += 256) m = fmaxf(m, src[t]);
#pragma unroll
    for (int off = 32; off > 0; off >>= 1) m = fmaxf(m, __shfl_down(m, off, 64));
    __shared__ float sm[4];
    if ((threadIdx.x & 63) == 0) sm[threadIdx.x >> 6] = m;
    __syncthreads();
    if (threadIdx.x == 0)
        maxes[blockIdx.x] = fmaxf(fmaxf(sm[0], sm[1]), fmaxf(sm[2], sm[3]));
}

// ---- kernel 4: transpose + bf16 convert: src[J][F] f32 -> dst[F][J] bf16 ----
__global__ __launch_bounds__(256) void k_prep(
    const float* __restrict__ src, unsigned short* __restrict__ dst,
    const int J, const int F) {
    __shared__ float tile[64][65];
    const int t = threadIdx.x;
    const int j0 = blockIdx.x * 64, f0 = blockIdx.y * 64;
#pragma unroll
    for (int p = 0; p < 4; ++p) {
        int j = (t >> 4) + p * 16;
        float4 v = *(const float4*)(src + (size_t)(j0 + j) * F + f0 + (t & 15) * 4);
        tile[j][(t & 15) * 4 + 0] = v.x;
        tile[j][(t & 15) * 4 + 1] = v.y;
        tile[j][(t & 15) * 4 + 2] = v.z;
        tile[j][(t & 15) * 4 + 3] = v.w;
    }
    __syncthreads();
#pragma unroll
    for (int p = 0; p < 2; ++p) {
        int f = (t >> 3) + p * 32;
        int c = t & 7;
        bf16x8 v;
#pragma unroll
        for (int e = 0; e < 8; ++e) v[e] = (short)f2bf(tile[c * 8 + e][f]);
        *(bf16x8*)(dst + (size_t)(f0 + f) * J + j0 + c * 8) = v;
    }
}

// ---- kernel 5: node attention aggregation, MFMA, double-buffered + prefetch ----
__global__ __launch_bounds__(256) void k_node_att(
    const unsigned short* __restrict__ Xt,   // [128][4096] bf16
    const int* __restrict__ adj,
    const float* __restrict__ alpha, const float* __restrict__ beta,
    const float* __restrict__ maxes,
    float* __restrict__ accP, float* __restrict__ zP, float* __restrict__ degP) {
    __shared__ unsigned short xlds[2][128 * 64];  // 32 KB, XOR-swizzled chunks
    __shared__ unsigned short wlds[2][4 * 512];   // 8 KB  [kb*2+nb][lane*8]
    __shared__ float bb[512];
    __shared__ float zred[8][32];
    __shared__ float dred[8][32];
    const int t = threadIdx.x;
    const int i0 = blockIdx.x * 32;
    const int bj = blockIdx.y;
    const int j0 = bj * (N_NODES / NJS);       // 512 j per block
    const int il = t & 31;
    const int jg = t >> 5;                     // 0..7
    const float a_i = alpha[i0 + il];
    const float m_i = lrelu(a_i + maxes[0]);
    if (t < 128) *(float4*)&bb[t * 4] = *(const float4*)(beta + j0 + t * 4);
    const int l = t & 63, wid = t >> 6;
    const int wm = wid >> 1, wn = wid & 1;
    const int l15 = l & 15, l4 = l >> 4;
    const int sf = t >> 3, sc = t & 7;         // stage: rows sf+32p, chunk sc
    const int xswz = (sc ^ (sf & 7)) * 8;
    const int wdst = ((jg >> 2) * 2 + (il >> 4)) * 512 + ((il & 15) + 16 * (jg & 3)) * 8;
    f32x4 acc[4] = {{0,0,0,0},{0,0,0,0},{0,0,0,0},{0,0,0,0}};
    float zacc = 0.f, dacc = 0.f;

    const int* mp0 = adj + (size_t)(j0 + jg * 8) * N_NODES + i0 + il;
    const unsigned short* xs0 = Xt + (size_t)sf * N_NODES + j0 + sc * 8;

    // prologue: loads for ks=0
    int mk[8];
#pragma unroll
    for (int e = 0; e < 8; ++e) mk[e] = mp0[(size_t)e * N_NODES];
    bf16x8 xv0 = *(const bf16x8*)(xs0);
    bf16x8 xv1 = *(const bf16x8*)(xs0 + (size_t)32 * N_NODES);
    bf16x8 xv2 = *(const bf16x8*)(xs0 + (size_t)64 * N_NODES);
    bf16x8 xv3 = *(const bf16x8*)(xs0 + (size_t)96 * N_NODES);
    __syncthreads();   // bb visible

    int buf = 0;
    for (int ks = 0; ks < 8; ++ks) {
        const int jb = ks * 64;
        // w-gen from prefetched regs
        bf16x8 wfrag;
#pragma unroll
        for (int e = 0; e < 8; ++e) {
            float s = lrelu(a_i + bb[jb + jg * 8 + e]);
            float w = mk[e] > 0 ? __expf(s - m_i) : 0.f;
            zacc += w;
            dacc += (float)mk[e];
            wfrag[e] = (short)f2bf(w);
        }
        // stage LDS
        *(bf16x8*)&xlds[buf][(sf +  0) * 64 + xswz] = xv0;
        *(bf16x8*)&xlds[buf][(sf + 32) * 64 + xswz] = xv1;
        *(bf16x8*)&xlds[buf][(sf + 64) * 64 + xswz] = xv2;
        *(bf16x8*)&xlds[buf][(sf + 96) * 64 + xswz] = xv3;
        *(bf16x8*)&wlds[buf][wdst] = wfrag;
        // prefetch next iteration
        if (ks + 1 < 8) {
            const int jbn = jb + 64;
            const int* mp = mp0 + (size_t)jbn * N_NODES;
#pragma unroll
            for (int e = 0; e < 8; ++e) mk[e] = mp[(size_t)e * N_NODES];
            const unsigned short* xs = xs0 + jbn;
            xv0 = *(const bf16x8*)(xs);
            xv1 = *(const bf16x8*)(xs + (size_t)32 * N_NODES);
            xv2 = *(const bf16x8*)(xs + (size_t)64 * N_NODES);
            xv3 = *(const bf16x8*)(xs + (size_t)96 * N_NODES);
        }
        __syncthreads();   // publish buf
#pragma unroll
        for (int kb = 0; kb < 2; ++kb) {
            bf16x8 b = *(const bf16x8*)&wlds[buf][(kb * 2 + wn) * 512 + l * 8];
#pragma unroll
            for (int mi = 0; mi < 4; ++mi) {
                const int fr = wm * 64 + mi * 16 + l15;
                bf16x8 a = *(const bf16x8*)&xlds[buf][fr * 64 + (((kb * 4 + l4) ^ (fr & 7)) * 8)];
                acc[mi] = __builtin_amdgcn_mfma_f32_16x16x32_bf16(a, b, acc[mi], 0, 0, 0);
            }
        }
        buf ^= 1;
    }
    zred[jg][il] = zacc;
    dred[jg][il] = dacc;
    __syncthreads();
    if (t < 32) {
        float z = 0.f, d = 0.f;
#pragma unroll
        for (int g = 0; g < 8; ++g) { z += zred[g][t]; d += dred[g][t]; }
        zP[bj * N_NODES + i0 + t] = z;
        degP[bj * N_NODES + i0 + t] = d;
    }
    const int ig = i0 + wn * 16 + l15;
#pragma unroll
    for (int mi = 0; mi < 4; ++mi) {
        const int fg = wm * 64 + mi * 16 + l4 * 4;
        *(f32x4*)(accP + ((size_t)bj * N_NODES + ig) * FN + fg) = acc[mi];
    }
}

// ---- kernel 6: edge attention aggregation, MFMA, KSTEP=64, dbuf + prefetch ----
__global__ __launch_bounds__(256) void k_edge_att(
    const unsigned short* __restrict__ Xt,   // [64][16384] bf16
    const int* __restrict__ eadj,
    const float* __restrict__ gamma, const float* __restrict__ betaE,
    const float* __restrict__ maxes,
    float* __restrict__ accP, float* __restrict__ zP, float* __restrict__ degP) {
    __shared__ unsigned short xlds[2][64 * 64];   // 16 KB, swizzled chunks
    __shared__ unsigned short wlds[2][8 * 512];   // 16 KB [kb*4+nb][lane*8]
    __shared__ float bb[1024];
    __shared__ float zred[4][64];
    __shared__ float dred[4][64];
    const int t = threadIdx.x;
    const int i0 = blockIdx.x * 64;
    const int bj = blockIdx.y;
    const int j0 = bj * (N_EDGES / EJS);       // 1024 j per block
    const int il = t & 63;
    const int jg = t >> 6;                     // 0..3 (wave id)
    const float g_i = gamma[i0 + il];
    const float m_i = lrelu(g_i + maxes[1]);
    *(float4*)&bb[t * 4] = *(const float4*)(betaE + j0 + t * 4);
    const int l = t & 63, wid = t >> 6;
    const int wm = wid >> 1, wn = wid & 1;
    const int l15 = l & 15, l4 = l >> 4;
    const int sf = t >> 2, sc = t & 3;         // stage: row sf, chunks sc / sc+4
    const int xd0 = sf * 64 + ((sc       ^ (sf & 7)) * 8);
    const int xd1 = sf * 64 + (((sc + 4) ^ (sf & 7)) * 8);
    const unsigned short* xsrc = Xt + (size_t)sf * N_EDGES + j0 + sc * 8;
    const int wl = (il & 15) + 16 * jg;        // lane-in-frag
    const int nb = il >> 4;
    f32x4 acc[2][2] = {{{0,0,0,0},{0,0,0,0}},{{0,0,0,0},{0,0,0,0}}};
    float zacc = 0.f, dacc = 0.f;

    const int* mp0 = eadj + (size_t)(j0 + jg * 8) * N_NODES + i0 + il;

    // prologue loads (ks=0)
    int mk0[8], mk1[8];
#pragma unroll
    for (int e = 0; e < 8; ++e) mk0[e] = mp0[(size_t)e * N_NODES];
#pragma unroll
    for (int e = 0; e < 8; ++e) mk1[e] = mp0[(size_t)(32 + e) * N_NODES];
    bf16x8 xv0 = *(const bf16x8*)(xsrc);
    bf16x8 xv1 = *(const bf16x8*)(xsrc + 32);
    __syncthreads();   // bb visible

    int buf = 0;
    for (int ks = 0; ks < 16; ++ks) {
        const int jb = ks * 64;
        // w-gen from prefetched regs
        bf16x8 wf0, wf1;
#pragma unroll
        for (int e = 0; e < 8; ++e) {
            float s0 = lrelu(g_i + bb[jb + jg * 8 + e]);
            float w0 = mk0[e] > 0 ? __expf(s0 - m_i) : 0.f;
            float s1 = lrelu(g_i + bb[jb + 32 + jg * 8 + e]);
            float w1 = mk1[e] > 0 ? __expf(s1 - m_i) : 0.f;
            zacc += w0 + w1;
            dacc += (float)(mk0[e] + mk1[e]);
            wf0[e] = (short)f2bf(w0);
            wf1[e] = (short)f2bf(w1);
        }
        // stage LDS
        *(bf16x8*)&xlds[buf][xd0] = xv0;
        *(bf16x8*)&xlds[buf][xd1] = xv1;
        *(bf16x8*)&wlds[buf][(0 * 4 + nb) * 512 + wl * 8] = wf0;
        *(bf16x8*)&wlds[buf][(1 * 4 + nb) * 512 + wl * 8] = wf1;
        // prefetch next iteration
        if (ks + 1 < 16) {
            const int jbn = jb + 64;
            const int* mp = mp0 + (size_t)jbn * N_NODES;
#pragma unroll
            for (int e = 0; e < 8; ++e) mk0[e] = mp[(size_t)e * N_NODES];
#pragma unroll
            for (int e = 0; e < 8; ++e) mk1[e] = mp[(size_t)(32 + e) * N_NODES];
            xv0 = *(const bf16x8*)(xsrc + jbn);
            xv1 = *(const bf16x8*)(xsrc + jbn + 32);
        }
        __syncthreads();   // publish buf
#pragma unroll
        for (int kb = 0; kb < 2; ++kb) {
            bf16x8 b0 = *(const bf16x8*)&wlds[buf][(kb * 4 + wn * 2 + 0) * 512 + l * 8];
            bf16x8 b1 = *(const bf16x8*)&wlds[buf][(kb * 4 + wn * 2 + 1) * 512 + l * 8];
#pragma unroll
            for (int mi = 0; mi < 2; ++mi) {
                const int fr = wm * 32 + mi * 16 + l15;
                bf16x8 a = *(const bf16x8*)&xlds[buf][fr * 64 + (((kb * 4 + l4) ^ (fr & 7)) * 8)];
                acc[mi][0] = __builtin_amdgcn_mfma_f32_16x16x32_bf16(a, b0, acc[mi][0], 0, 0, 0);
                acc[mi][1] = __builtin_amdgcn_mfma_f32_16x16x32_bf16(a, b1, acc[mi][1], 0, 0, 0);
            }
        }
        buf ^= 1;
    }
    zred[jg][il] = zacc;
    dred[jg][il] = dacc;
    __syncthreads();
    if (t < 64) {
        float z = zred[0][t] + zred[1][t] + zred[2][t] + zred[3][t];
        float d = dred[0][t] + dred[1][t] + dred[2][t] + dred[3][t];
        zP[bj * N_NODES + i0 + t] = z;
        degP[bj * N_NODES + i0 + t] = d;
    }
    const size_t obase = (size_t)bj * N_NODES;
#pragma unroll
    for (int mi = 0; mi < 2; ++mi) {
#pragma unroll
        for (int p = 0; p < 2; ++p) {
            int ig = i0 + wn * 32 + p * 16 + l15;
            int fg = wm * 32 + mi * 16 + l4 * 4;
            *(f32x4*)(accP + (obase + ig) * FE + fg) = acc[mi][p];
        }
    }
}

// ---- kernel 7: node epilogue ----
__global__ __launch_bounds__(256) void k_node_out(
    const float* __restrict__ accP, const float* __restrict__ zP,
    const float* __restrict__ degP, const float* __restrict__ Wn,
    float* __restrict__ out) {
    __shared__ float ml[4][FN];
    const int wv = threadIdx.x >> 6, ln = threadIdx.x & 63;
    const int i = blockIdx.x * 4 + wv;
    float s0 = 0.f, s1 = 0.f;
#pragma unroll
    for (int js = 0; js < NJS; ++js) {
        float2 v = *(const float2*)(accP + ((size_t)js * N_NODES + i) * FN + ln * 2);
        s0 += v.x; s1 += v.y;
    }
    float z = 0.f, d = 0.f;
#pragma unroll
    for (int js = 0; js < NJS; ++js) { z += zP[js * N_NODES + i]; d += degP[js * N_NODES + i]; }
    float zd = z * d;
    float inv = zd > 0.f ? 1.f / zd : 0.f;
    ml[wv][ln * 2] = s0 * inv; ml[wv][ln * 2 + 1] = s1 * inv;
    __syncthreads();
    float o0 = 0.f, o1 = 0.f;
#pragma unroll 8
    for (int k = 0; k < FN; ++k) {
        float mvv = ml[wv][k];
        float2 w2 = *(const float2*)(Wn + (size_t)k * FN + ln * 2);
        o0 = fmaf(mvv, w2.x, o0); o1 = fmaf(mvv, w2.y, o1);
    }
    out[(size_t)i * 192 + ln * 2] = lrelu(o0);
    out[(size_t)i * 192 + ln * 2 + 1] = lrelu(o1);
}

// ---- kernel 8: edge epilogue ----
__global__ __launch_bounds__(256) void k_edge_out(
    const float* __restrict__ accP, const float* __restrict__ zP,
    const float* __restrict__ degP, const float* __restrict__ We,
    float* __restrict__ out) {
    __shared__ float ml[4][FE];
    const int wv = threadIdx.x >> 6, ln = threadIdx.x & 63;
    const int i = blockIdx.x * 4 + wv;
    float s = 0.f;
#pragma unroll
    for (int js = 0; js < EJS; ++js)
        s += accP[((size_t)js * N_NODES + i) * FE + ln];
    float z = 0.f, d = 0.f;
#pragma unroll
    for (int js = 0; js < EJS; ++js) { z += zP[js * N_NODES + i]; d += degP[js * N_NODES + i]; }
    float zd = z * d;
    float inv = zd > 0.f ? 1.f / zd : 0.f;
    ml[wv][ln] = s * inv;
    __syncthreads();
    float o = 0.f;
#pragma unroll 8
    for (int k = 0; k < FE; ++k)
        o = fmaf(ml[wv][k], We[(size_t)k * FE + ln], o);
    out[(size_t)i * 192 + 128 + ln] = lrelu(o);
}

extern "C" void kernel_launch(void* const* d_in, const int* in_sizes, int n_in,
                              void* d_out, int out_size, void* d_ws, size_t ws_size,
                              hipStream_t stream) {
    (void)in_sizes; (void)n_in; (void)out_size; (void)ws_size;
    const float* nf   = (const float*)d_in[0];
    const float* ef   = (const float*)d_in[1];
    const int*   adj  = (const int*)d_in[2];
    const int*   eadj = (const int*)d_in[3];
    const float* Wn   = (const float*)d_in[4];
    const float* We   = (const float*)d_in[5];
    const float* pvn  = (const float*)d_in[6];
    const float* pve  = (const float*)d_in[7];
    float* out = (float*)d_out;

    float* alpha = (float*)d_ws;                       // 4096
    float* beta  = alpha + 4096;                       // 4096
    float* gamma = beta + 4096;                        // 4096
    float* betaE = gamma + 4096;                       // 16384
    float* maxes = betaE + 16384;                      // 64 (padded)
    unsigned short* XtN = (unsigned short*)(maxes + 64);          // 128*4096 bf16
    unsigned short* XtE = XtN + (size_t)FN * N_NODES;             // 64*16384 bf16
    float* accN = (float*)(XtE + (size_t)FE * N_EDGES);           // NJS*4096*128
    float* zN   = accN + (size_t)NJS * N_NODES * FN;
    float* degN = zN + (size_t)NJS * N_NODES;
    float* accE = degN + (size_t)NJS * N_NODES;                   // EJS*4096*64
    float* zE   = accE + (size_t)EJS * N_NODES * FE;
    float* degE = zE + (size_t)EJS * N_NODES;

    k_node_proj<<<N_NODES / 4, 256, 0, stream>>>(nf, Wn, pvn, pve, alpha, beta, gamma);
    k_edge_proj<<<N_EDGES / 4, 256, 0, stream>>>(ef, We, pve, betaE);
    k_maxes<<<2, 256, 0, stream>>>(beta, betaE, maxes);
    k_prep<<<dim3(N_NODES / 64, FN / 64), 256, 0, stream>>>(nf, XtN, N_NODES, FN);
    k_prep<<<dim3(N_EDGES / 64, FE / 64), 256, 0, stream>>>(ef, XtE, N_EDGES, FE);
    k_node_att<<<dim3(N_NODES / 32, NJS), 256, 0, stream>>>(XtN, adj, alpha, beta, maxes, accN, zN, degN);
    k_edge_att<<<dim3(N_NODES / 64, EJS), 256, 0, stream>>>(XtE, eadj, gamma, betaE, maxes, accE, zE, degE);
    k_node_out<<<N_NODES / 4, 256, 0, stream>>>(accN, zN, degN, Wn, out);
    k_edge_out<<<N_NODES / 4, 256, 0, stream>>>(accE, zE, degE, We, out);
}